// Round 2
// baseline (2559.262 us; speedup 1.0000x reference)
//
#include <hip/hip_runtime.h>
#include <algorithm>

#define FIN 24
#define NHID 64
#define NMIX 216
#define NOUT 6
#define BN_EPS 1e-5f

// ---------- small setup kernels ----------
__global__ void k_deg(const int* __restrict__ ei, int E, float* deg) {
    int e = blockIdx.x * blockDim.x + threadIdx.x;
    if (e < E) atomicAdd(&deg[ei[E + e]], 1.0f);
}

__global__ void k_dis(float* d, int n) {
    int i = blockIdx.x * blockDim.x + threadIdx.x;
    if (i < n) { float v = d[i]; d[i] = v > 0.f ? rsqrtf(v) : 0.f; }
}

__global__ void k_norm(const int* __restrict__ ei, int E, const float* __restrict__ dis,
                       float* __restrict__ nrm) {
    int e = blockIdx.x * blockDim.x + threadIdx.x;
    if (e < E) nrm[e] = -dis[ei[e]] * dis[ei[E + e]];
}

// dst = -src  (vectorized; n4 = n*FIN/4)
__global__ void k_initneg(const float* __restrict__ src, float* __restrict__ dst, int n4) {
    int i = blockIdx.x * blockDim.x + threadIdx.x;
    if (i < n4) {
        float4 v = reinterpret_cast<const float4*>(src)[i];
        reinterpret_cast<float4*>(dst)[i] = make_float4(-v.x, -v.y, -v.z, -v.w);
    }
}

// out[dst,f] += h[src,f] * norm[e] * scale; thread per (edge, 4-feat chunk)
__global__ void k_prop(const int* __restrict__ ei, int E, const float* __restrict__ nrm,
                       float scale, const float* __restrict__ h, float* __restrict__ out) {
    int idx = blockIdx.x * blockDim.x + threadIdx.x;
    if (idx >= E * 6) return;
    int e = idx / 6, q = idx - e * 6;
    int s = ei[e], d = ei[E + e];
    float w = nrm[e] * scale;
    float4 hv = *reinterpret_cast<const float4*>(h + (size_t)s * FIN + q * 4);
    float* o = out + (size_t)d * FIN + q * 4;
    atomicAdd(o + 0, hv.x * w);
    atomicAdd(o + 1, hv.y * w);
    atomicAdd(o + 2, hv.z * w);
    atomicAdd(o + 3, hv.w * w);
}

// acc[node][j] (=|+=) S1@Wa + S2@Wb (+bias).  lane=j, wave-uniform node.
// grid-stride; optional fused BN stats (sum/sumsq per j) via block reduce + atomics.
__global__ void k_gemv2(const float* __restrict__ S1, const float* __restrict__ S2,
                        const float* __restrict__ Wa, const float* __restrict__ Wb,
                        const float* __restrict__ bias, float* __restrict__ acc,
                        float* __restrict__ stats, int n) {
    int j = threadIdx.x & 63;
    int grp = threadIdx.x >> 6;  // 4 nodes per 256-thread block per iter
    float wa[FIN], wb[FIN];
#pragma unroll
    for (int f = 0; f < FIN; ++f) wa[f] = Wa[f * NHID + j];
#pragma unroll
    for (int f = 0; f < FIN; ++f) wb[f] = Wb[f * NHID + j];
    float sum = 0.f, sq = 0.f;
    for (int node = blockIdx.x * 4 + grp; node < n; node += gridDim.x * 4) {
        float a = bias ? bias[j] : acc[(size_t)node * NHID + j];
        const float* s1 = S1 + (size_t)node * FIN;
#pragma unroll
        for (int f = 0; f < FIN; ++f) a = fmaf(s1[f], wa[f], a);
        const float* s2 = S2 + (size_t)node * FIN;
#pragma unroll
        for (int f = 0; f < FIN; ++f) a = fmaf(s2[f], wb[f], a);
        acc[(size_t)node * NHID + j] = a;
        sum += a; sq = fmaf(a, a, sq);
    }
    if (stats) {
        __shared__ float rs[256], rq[256];
        rs[threadIdx.x] = sum; rq[threadIdx.x] = sq;
        __syncthreads();
        if (threadIdx.x < 64) {
            float s = rs[threadIdx.x] + rs[threadIdx.x + 64] + rs[threadIdx.x + 128] + rs[threadIdx.x + 192];
            float q = rq[threadIdx.x] + rq[threadIdx.x + 64] + rq[threadIdx.x + 128] + rq[threadIdx.x + 192];
            atomicAdd(&stats[threadIdx.x], s);
            atomicAdd(&stats[NHID + threadIdx.x], q);
        }
    }
}

// in-place BN + ReLU, float4 over [n][64]
__global__ void k_bnrelu4(float* acc, int n, const float* __restrict__ stats,
                          const float* __restrict__ g, const float* __restrict__ bt) {
    int i = blockIdx.x * blockDim.x + threadIdx.x;
    if (i >= n * (NHID / 4)) return;
    int f0 = (i & 15) * 4;
    float inv_n = 1.0f / (float)n;
    float4 v = reinterpret_cast<float4*>(acc)[i];
    float* vp = &v.x;
#pragma unroll
    for (int c = 0; c < 4; ++c) {
        int f = f0 + c;
        float m = stats[f] * inv_n;
        float var = stats[NHID + f] * inv_n - m * m;
        float sc = g[f] * rsqrtf(var + BN_EPS);
        float sh = fmaf(-m, sc, bt[f]);
        vp[c] = fmaxf(fmaf(vp[c], sc, sh), 0.f);
    }
    reinterpret_cast<float4*>(acc)[i] = v;
}

// segment-mean scatter
__global__ void k_scatter(const float* __restrict__ x, const int* __restrict__ cl,
                          int n, float* xp, float* cnt) {
    int idx = blockIdx.x * blockDim.x + threadIdx.x;
    if (idx >= n * FIN) return;
    int node = idx / FIN, f = idx - node * FIN;
    int c = cl[node];
    atomicAdd(&xp[c * FIN + f], x[idx]);
    if (f == 0) atomicAdd(&cnt[c], 1.f);
}

__global__ void k_divcnt(float* xp, const float* __restrict__ cnt, int c) {
    int idx = blockIdx.x * blockDim.x + threadIdx.x;
    if (idx >= c * FIN) return;
    xp[idx] = xp[idx] / fmaxf(cnt[idx / FIN], 1.f);
}

// fused: BN1+ReLU on acc1, gather h2[c1], h3[c2], concat x, @Wm + bm.
// wave per node: lane = hidden index; shfl-reduce 6 outputs.
__global__ void k_final(const float* __restrict__ acc1, const float* __restrict__ stats1,
                        const float* __restrict__ g1, const float* __restrict__ bt1,
                        const float* __restrict__ h2, const int* __restrict__ cl1,
                        const float* __restrict__ h3, const int* __restrict__ cl2,
                        const float* __restrict__ x, const float* __restrict__ Wm,
                        const float* __restrict__ bm, float* __restrict__ out, int n) {
    __shared__ float Wms[NMIX * NOUT];
    __shared__ float sc1[NHID], sh1[NHID];
    for (int i = threadIdx.x; i < NMIX * NOUT; i += blockDim.x) Wms[i] = Wm[i];
    if (threadIdx.x < NHID) {
        float inv_n = 1.0f / (float)n;
        float m = stats1[threadIdx.x] * inv_n;
        float v = stats1[NHID + threadIdx.x] * inv_n - m * m;
        float s = g1[threadIdx.x] * rsqrtf(v + BN_EPS);
        sc1[threadIdx.x] = s;
        sh1[threadIdx.x] = fmaf(-m, s, bt1[threadIdx.x]);
    }
    __syncthreads();
    int lane = threadIdx.x & 63;
    int node = blockIdx.x * 4 + (threadIdx.x >> 6);
    if (node >= n) return;
    float o0 = 0.f, o1 = 0.f, o2 = 0.f, o3 = 0.f, o4 = 0.f, o5 = 0.f;
    {   // h1 part
        float h = fmaxf(fmaf(acc1[(size_t)node * NHID + lane], sc1[lane], sh1[lane]), 0.f);
        const float* wr = &Wms[lane * NOUT];
        o0 = fmaf(h, wr[0], o0); o1 = fmaf(h, wr[1], o1); o2 = fmaf(h, wr[2], o2);
        o3 = fmaf(h, wr[3], o3); o4 = fmaf(h, wr[4], o4); o5 = fmaf(h, wr[5], o5);
    }
    {   // h2 part
        int c1 = cl1[node];
        float h = h2[(size_t)c1 * NHID + lane];
        const float* wr = &Wms[(NHID + lane) * NOUT];
        o0 = fmaf(h, wr[0], o0); o1 = fmaf(h, wr[1], o1); o2 = fmaf(h, wr[2], o2);
        o3 = fmaf(h, wr[3], o3); o4 = fmaf(h, wr[4], o4); o5 = fmaf(h, wr[5], o5);
    }
    {   // h3 part
        int c2 = cl2[node];
        float h = h3[(size_t)c2 * NHID + lane];
        const float* wr = &Wms[(2 * NHID + lane) * NOUT];
        o0 = fmaf(h, wr[0], o0); o1 = fmaf(h, wr[1], o1); o2 = fmaf(h, wr[2], o2);
        o3 = fmaf(h, wr[3], o3); o4 = fmaf(h, wr[4], o4); o5 = fmaf(h, wr[5], o5);
    }
    if (lane < FIN) {   // raw-x part
        float h = x[(size_t)node * FIN + lane];
        const float* wr = &Wms[(3 * NHID + lane) * NOUT];
        o0 = fmaf(h, wr[0], o0); o1 = fmaf(h, wr[1], o1); o2 = fmaf(h, wr[2], o2);
        o3 = fmaf(h, wr[3], o3); o4 = fmaf(h, wr[4], o4); o5 = fmaf(h, wr[5], o5);
    }
#pragma unroll
    for (int d = 32; d; d >>= 1) {
        o0 += __shfl_xor(o0, d, 64); o1 += __shfl_xor(o1, d, 64);
        o2 += __shfl_xor(o2, d, 64); o3 += __shfl_xor(o3, d, 64);
        o4 += __shfl_xor(o4, d, 64); o5 += __shfl_xor(o5, d, 64);
    }
    if (lane == 0) {
        float* op = out + (size_t)node * NOUT;
        op[0] = o0 + bm[0]; op[1] = o1 + bm[1]; op[2] = o2 + bm[2];
        op[3] = o3 + bm[3]; op[4] = o4 + bm[4]; op[5] = o5 + bm[5];
    }
}

extern "C" void kernel_launch(void* const* d_in, const int* in_sizes, int n_in,
                              void* d_out, int out_size, void* d_ws, size_t ws_size,
                              hipStream_t stream) {
    const int N = 200000, E = 800000;
    const int C1n = 20000, E1 = 80000;
    const int C2n = 2000, E2 = 8000;

    const float* x  = (const float*)d_in[0];
    const int* ei   = (const int*)d_in[1];
    const int* cl1  = (const int*)d_in[2];
    const int* cl2  = (const int*)d_in[3];
    const int* eic1 = (const int*)d_in[4];
    const int* eic2 = (const int*)d_in[5];
    const float* W1 = (const float*)d_in[6];  const float* b1 = (const float*)d_in[7];
    const float* g1 = (const float*)d_in[8];  const float* bt1 = (const float*)d_in[9];
    const float* W2 = (const float*)d_in[10]; const float* b2 = (const float*)d_in[11];
    const float* g2 = (const float*)d_in[12]; const float* bt2 = (const float*)d_in[13];
    const float* W3 = (const float*)d_in[14]; const float* b3 = (const float*)d_in[15];
    const float* g3 = (const float*)d_in[16]; const float* bt3 = (const float*)d_in[17];
    const float* Wm = (const float*)d_in[18]; const float* bm = (const float*)d_in[19];

    float* w = (float*)d_ws;
    size_t off = 0;
    auto alloc = [&](size_t nf) { float* p = w + off; off += nf; return p; };
    // --- zero-region (atomic accumulators + first prop targets) ---
    float* B1_0 = alloc((size_t)N * FIN);
    float* B2_0 = alloc((size_t)C1n * FIN);
    float* B3_0 = alloc((size_t)C2n * FIN);
    float* dis1 = alloc(N); float* dis2 = alloc(C1n); float* dis3 = alloc(C2n);
    float* st1 = alloc(128); float* st2 = alloc(128); float* st3 = alloc(128);
    float* xp1 = alloc((size_t)C1n * FIN); float* cnt1 = alloc(C1n);
    float* xp2 = alloc((size_t)C2n * FIN); float* cnt2 = alloc(C2n);
    size_t zero_floats = off;
    // --- fully-overwritten region ---
    float* B1_1 = alloc((size_t)N * FIN);  float* B1_2 = alloc((size_t)N * FIN);
    float* B2_1 = alloc((size_t)C1n * FIN); float* B2_2 = alloc((size_t)C1n * FIN);
    float* B3_1 = alloc((size_t)C2n * FIN); float* B3_2 = alloc((size_t)C2n * FIN);
    float* acc1 = alloc((size_t)N * NHID);
    float* acc2 = alloc((size_t)C1n * NHID);
    float* acc3 = alloc((size_t)C2n * NHID);
    float* nrm1 = alloc(E); float* nrm2 = alloc(E1); float* nrm3 = alloc(E2);
    if (off * sizeof(float) > ws_size) return;  // fail visibly if ws too small

    hipMemsetAsync(d_ws, 0, zero_floats * sizeof(float), stream);

    const int T = 256;
    auto cdiv = [](int a, int b) { return (a + b - 1) / b; };

    auto branch = [&](const float* xin, int n, const int* e, int Ecnt,
                      const float* W, const float* bb, float* dis, float* nrm,
                      float* B0, float* Bb1, float* Bb2, float* acc, float* st) {
        int ge = cdiv(Ecnt, T), gn = cdiv(n, T);
        int gp = cdiv(Ecnt * 6, T);          // prop: thread per (edge, 4 feats)
        int gneg = cdiv(n * 6, T);           // initneg: float4
        int gg = std::min(cdiv(n, 4), 1280); // gemv grid-stride
        const int WSZ = FIN * NHID;
        k_deg<<<ge, T, 0, stream>>>(e, Ecnt, dis);
        k_dis<<<gn, T, 0, stream>>>(dis, n);
        k_norm<<<ge, T, 0, stream>>>(e, Ecnt, dis, nrm);
        // Tx1 -> B0 (pre-zeroed)
        k_prop<<<gp, T, 0, stream>>>(e, Ecnt, nrm, 1.0f, xin, B0);
        // acc = b + x@W0 + Tx1@W1
        k_gemv2<<<gg, T, 0, stream>>>(xin, B0, W, W + WSZ, bb, acc, nullptr, n);
        // Tx2 = 2*prop(Tx1) - x  -> Bb1
        k_initneg<<<gneg, T, 0, stream>>>(xin, Bb1, n * 6);
        k_prop<<<gp, T, 0, stream>>>(e, Ecnt, nrm, 2.0f, B0, Bb1);
        // Tx3 = 2*prop(Tx2) - Tx1 -> Bb2
        k_initneg<<<gneg, T, 0, stream>>>(B0, Bb2, n * 6);
        k_prop<<<gp, T, 0, stream>>>(e, Ecnt, nrm, 2.0f, Bb1, Bb2);
        // acc += Tx2@W2 + Tx3@W3
        k_gemv2<<<gg, T, 0, stream>>>(Bb1, Bb2, W + 2 * WSZ, W + 3 * WSZ, nullptr, acc, nullptr, n);
        // Tx4 = 2*prop(Tx3) - Tx2 -> B0
        k_initneg<<<gneg, T, 0, stream>>>(Bb1, B0, n * 6);
        k_prop<<<gp, T, 0, stream>>>(e, Ecnt, nrm, 2.0f, Bb2, B0);
        // Tx5 = 2*prop(Tx4) - Tx3 -> Bb1
        k_initneg<<<gneg, T, 0, stream>>>(Bb2, Bb1, n * 6);
        k_prop<<<gp, T, 0, stream>>>(e, Ecnt, nrm, 2.0f, B0, Bb1);
        // acc += Tx4@W4 + Tx5@W5, fused BN stats
        k_gemv2<<<gg, T, 0, stream>>>(B0, Bb1, W + 4 * WSZ, W + 5 * WSZ, nullptr, acc, st, n);
    };

    // branch 1: full graph
    branch(x, N, ei, E, W1, b1, dis1, nrm1, B1_0, B1_1, B1_2, acc1, st1);
    // branch 2: cluster1 pooled graph
    k_scatter<<<cdiv(N * FIN, T), T, 0, stream>>>(x, cl1, N, xp1, cnt1);
    k_divcnt<<<cdiv(C1n * FIN, T), T, 0, stream>>>(xp1, cnt1, C1n);
    branch(xp1, C1n, eic1, E1, W2, b2, dis2, nrm2, B2_0, B2_1, B2_2, acc2, st2);
    k_bnrelu4<<<cdiv(C1n * 16, T), T, 0, stream>>>(acc2, C1n, st2, g2, bt2);
    // branch 3: cluster2 pooled graph
    k_scatter<<<cdiv(N * FIN, T), T, 0, stream>>>(x, cl2, N, xp2, cnt2);
    k_divcnt<<<cdiv(C2n * FIN, T), T, 0, stream>>>(xp2, cnt2, C2n);
    branch(xp2, C2n, eic2, E2, W3, b3, dis3, nrm3, B3_0, B3_1, B3_2, acc3, st3);
    k_bnrelu4<<<cdiv(C2n * 16, T), T, 0, stream>>>(acc3, C2n, st3, g3, bt3);
    // final fused mix (BN1+ReLU folded in)
    k_final<<<cdiv(N, 4), T, 0, stream>>>(acc1, st1, g1, bt1, acc2, cl1, acc3, cl2,
                                          x, Wm, bm, (float*)d_out, N);
}

// Round 3
// 927.250 us; speedup vs baseline: 2.7601x; 2.7601x over previous
//
#include <hip/hip_runtime.h>
#include <algorithm>

#define FIN 24
#define NHID 64
#define NMIX 216
#define NOUT 6
#define BN_EPS 1e-5f

// ---------- CSR build ----------
__global__ void k_hist(const int* __restrict__ ei, int E, int* deg) {
    int e = blockIdx.x * blockDim.x + threadIdx.x;
    if (e < E) atomicAdd(&deg[ei[E + e]], 1);
}

__global__ void k_dis(const int* __restrict__ deg, float* dis, int n) {
    int i = blockIdx.x * blockDim.x + threadIdx.x;
    if (i < n) { int v = deg[i]; dis[i] = v > 0 ? rsqrtf((float)v) : 0.f; }
}

// block-local exclusive scan over deg (n+1 elements, deg[i>=n]:=0); totals -> bsum
__global__ void k_scan_local(const int* __restrict__ deg, int n, int* rowptr, int* bsum) {
    __shared__ int s[256];
    int i = blockIdx.x * 256 + threadIdx.x;
    int v = (i < n) ? deg[i] : 0;
    s[threadIdx.x] = v;
    __syncthreads();
#pragma unroll
    for (int off = 1; off < 256; off <<= 1) {
        int x = (threadIdx.x >= off) ? s[threadIdx.x - off] : 0;
        __syncthreads();
        s[threadIdx.x] += x;
        __syncthreads();
    }
    if (i <= n) rowptr[i] = s[threadIdx.x] - v;  // exclusive
    if (threadIdx.x == 255) bsum[blockIdx.x] = s[255];
}

// single-block exclusive scan of bsum[nb] in place
__global__ void k_scan_bsum(int* bsum, int nb) {
    __shared__ int s[256];
    int carry = 0;
    for (int base = 0; base < nb; base += 256) {
        int i = base + threadIdx.x;
        int v = (i < nb) ? bsum[i] : 0;
        s[threadIdx.x] = v;
        __syncthreads();
#pragma unroll
        for (int off = 1; off < 256; off <<= 1) {
            int x = (threadIdx.x >= off) ? s[threadIdx.x - off] : 0;
            __syncthreads();
            s[threadIdx.x] += x;
            __syncthreads();
        }
        if (i < nb) bsum[i] = s[threadIdx.x] - v + carry;
        carry += s[255];
        __syncthreads();
    }
}

__global__ void k_scan_add(int* rowptr, const int* __restrict__ bsum, int n) {
    int i = blockIdx.x * 256 + threadIdx.x;
    if (i <= n) rowptr[i] += bsum[blockIdx.x];
}

// fill CSR: col=src, val=-dis[src]*dis[dst]
__global__ void k_fill(const int* __restrict__ ei, int E, const float* __restrict__ dis,
                       const int* __restrict__ rowptr, int* fill,
                       int* __restrict__ col, float* __restrict__ val) {
    int e = blockIdx.x * blockDim.x + threadIdx.x;
    if (e >= E) return;
    int s = ei[e], d = ei[E + e];
    int slot = rowptr[d] + atomicAdd(&fill[d], 1);
    col[slot] = s;
    val[slot] = -dis[s] * dis[d];
}

// ---------- gather prop: out[d] = scale*sum_e val[e]*h[col[e]] (- prev[d]) ----------
// thread per (dst, float4 chunk); prev may alias out (per-element in-place).
__global__ void k_propg(const int* __restrict__ rowptr, const int* __restrict__ col,
                        const float* __restrict__ val, float scale,
                        const float* __restrict__ h, const float* __restrict__ prev,
                        float* __restrict__ out, int n) {
    int idx = blockIdx.x * blockDim.x + threadIdx.x;
    if (idx >= n * 6) return;
    int d = idx / 6, q = idx - d * 6;
    int beg = rowptr[d], end = rowptr[d + 1];
    float ax = 0.f, ay = 0.f, az = 0.f, aw = 0.f;
    for (int e = beg; e < end; ++e) {
        float w = val[e];
        float4 hv = *reinterpret_cast<const float4*>(h + (size_t)col[e] * FIN + q * 4);
        ax = fmaf(w, hv.x, ax); ay = fmaf(w, hv.y, ay);
        az = fmaf(w, hv.z, az); aw = fmaf(w, hv.w, aw);
    }
    float4 r;
    if (prev) {
        const float4 pv = *reinterpret_cast<const float4*>(prev + (size_t)idx * 4);
        r = make_float4(fmaf(scale, ax, -pv.x), fmaf(scale, ay, -pv.y),
                        fmaf(scale, az, -pv.z), fmaf(scale, aw, -pv.w));
    } else {
        r = make_float4(scale * ax, scale * ay, scale * az, scale * aw);
    }
    *reinterpret_cast<float4*>(out + (size_t)idx * 4) = r;
}

// acc[node][j] (=|+=) S1@Wa + S2@Wb (+bias); lane=j, wave-uniform node; opt BN stats.
__global__ void k_gemv2(const float* __restrict__ S1, const float* __restrict__ S2,
                        const float* __restrict__ Wa, const float* __restrict__ Wb,
                        const float* __restrict__ bias, float* __restrict__ acc,
                        float* __restrict__ stats, int n) {
    int j = threadIdx.x & 63;
    int grp = threadIdx.x >> 6;
    float wa[FIN], wb[FIN];
#pragma unroll
    for (int f = 0; f < FIN; ++f) wa[f] = Wa[f * NHID + j];
#pragma unroll
    for (int f = 0; f < FIN; ++f) wb[f] = Wb[f * NHID + j];
    float sum = 0.f, sq = 0.f;
    for (int node = blockIdx.x * 4 + grp; node < n; node += gridDim.x * 4) {
        float a = bias ? bias[j] : acc[(size_t)node * NHID + j];
        const float* s1 = S1 + (size_t)node * FIN;
#pragma unroll
        for (int f = 0; f < FIN; ++f) a = fmaf(s1[f], wa[f], a);
        const float* s2 = S2 + (size_t)node * FIN;
#pragma unroll
        for (int f = 0; f < FIN; ++f) a = fmaf(s2[f], wb[f], a);
        acc[(size_t)node * NHID + j] = a;
        sum += a; sq = fmaf(a, a, sq);
    }
    if (stats) {
        __shared__ float rs[256], rq[256];
        rs[threadIdx.x] = sum; rq[threadIdx.x] = sq;
        __syncthreads();
        if (threadIdx.x < 64) {
            float s = rs[threadIdx.x] + rs[threadIdx.x + 64] + rs[threadIdx.x + 128] + rs[threadIdx.x + 192];
            float q = rq[threadIdx.x] + rq[threadIdx.x + 64] + rq[threadIdx.x + 128] + rq[threadIdx.x + 192];
            atomicAdd(&stats[threadIdx.x], s);
            atomicAdd(&stats[NHID + threadIdx.x], q);
        }
    }
}

// in-place BN + ReLU, float4 over [n][64]
__global__ void k_bnrelu4(float* acc, int n, const float* __restrict__ stats,
                          const float* __restrict__ g, const float* __restrict__ bt) {
    int i = blockIdx.x * blockDim.x + threadIdx.x;
    if (i >= n * (NHID / 4)) return;
    int f0 = (i & 15) * 4;
    float inv_n = 1.0f / (float)n;
    float4 v = reinterpret_cast<float4*>(acc)[i];
    float* vp = &v.x;
#pragma unroll
    for (int c = 0; c < 4; ++c) {
        int f = f0 + c;
        float m = stats[f] * inv_n;
        float var = stats[NHID + f] * inv_n - m * m;
        float sc = g[f] * rsqrtf(var + BN_EPS);
        float sh = fmaf(-m, sc, bt[f]);
        vp[c] = fmaxf(fmaf(vp[c], sc, sh), 0.f);
    }
    reinterpret_cast<float4*>(acc)[i] = v;
}

// segment-mean scatter (small; keep atomic form)
__global__ void k_scatter(const float* __restrict__ x, const int* __restrict__ cl,
                          int n, float* xp, float* cnt) {
    int idx = blockIdx.x * blockDim.x + threadIdx.x;
    if (idx >= n * FIN) return;
    int node = idx / FIN, f = idx - node * FIN;
    int c = cl[node];
    atomicAdd(&xp[c * FIN + f], x[idx]);
    if (f == 0) atomicAdd(&cnt[c], 1.f);
}

__global__ void k_divcnt(float* xp, const float* __restrict__ cnt, int c) {
    int idx = blockIdx.x * blockDim.x + threadIdx.x;
    if (idx >= c * FIN) return;
    xp[idx] = xp[idx] / fmaxf(cnt[idx / FIN], 1.f);
}

// fused: BN1+ReLU on acc1, gather h2[c1], h3[c2], concat x, @Wm + bm. wave/node.
__global__ void k_final(const float* __restrict__ acc1, const float* __restrict__ stats1,
                        const float* __restrict__ g1, const float* __restrict__ bt1,
                        const float* __restrict__ h2, const int* __restrict__ cl1,
                        const float* __restrict__ h3, const int* __restrict__ cl2,
                        const float* __restrict__ x, const float* __restrict__ Wm,
                        const float* __restrict__ bm, float* __restrict__ out, int n) {
    __shared__ float Wms[NMIX * NOUT];
    __shared__ float sc1[NHID], sh1[NHID];
    for (int i = threadIdx.x; i < NMIX * NOUT; i += blockDim.x) Wms[i] = Wm[i];
    if (threadIdx.x < NHID) {
        float inv_n = 1.0f / (float)n;
        float m = stats1[threadIdx.x] * inv_n;
        float v = stats1[NHID + threadIdx.x] * inv_n - m * m;
        float s = g1[threadIdx.x] * rsqrtf(v + BN_EPS);
        sc1[threadIdx.x] = s;
        sh1[threadIdx.x] = fmaf(-m, s, bt1[threadIdx.x]);
    }
    __syncthreads();
    int lane = threadIdx.x & 63;
    int node = blockIdx.x * 4 + (threadIdx.x >> 6);
    if (node >= n) return;
    float o0 = 0.f, o1 = 0.f, o2 = 0.f, o3 = 0.f, o4 = 0.f, o5 = 0.f;
    {
        float h = fmaxf(fmaf(acc1[(size_t)node * NHID + lane], sc1[lane], sh1[lane]), 0.f);
        const float* wr = &Wms[lane * NOUT];
        o0 = fmaf(h, wr[0], o0); o1 = fmaf(h, wr[1], o1); o2 = fmaf(h, wr[2], o2);
        o3 = fmaf(h, wr[3], o3); o4 = fmaf(h, wr[4], o4); o5 = fmaf(h, wr[5], o5);
    }
    {
        int c1 = cl1[node];
        float h = h2[(size_t)c1 * NHID + lane];
        const float* wr = &Wms[(NHID + lane) * NOUT];
        o0 = fmaf(h, wr[0], o0); o1 = fmaf(h, wr[1], o1); o2 = fmaf(h, wr[2], o2);
        o3 = fmaf(h, wr[3], o3); o4 = fmaf(h, wr[4], o4); o5 = fmaf(h, wr[5], o5);
    }
    {
        int c2 = cl2[node];
        float h = h3[(size_t)c2 * NHID + lane];
        const float* wr = &Wms[(2 * NHID + lane) * NOUT];
        o0 = fmaf(h, wr[0], o0); o1 = fmaf(h, wr[1], o1); o2 = fmaf(h, wr[2], o2);
        o3 = fmaf(h, wr[3], o3); o4 = fmaf(h, wr[4], o4); o5 = fmaf(h, wr[5], o5);
    }
    if (lane < FIN) {
        float h = x[(size_t)node * FIN + lane];
        const float* wr = &Wms[(3 * NHID + lane) * NOUT];
        o0 = fmaf(h, wr[0], o0); o1 = fmaf(h, wr[1], o1); o2 = fmaf(h, wr[2], o2);
        o3 = fmaf(h, wr[3], o3); o4 = fmaf(h, wr[4], o4); o5 = fmaf(h, wr[5], o5);
    }
#pragma unroll
    for (int d = 32; d; d >>= 1) {
        o0 += __shfl_xor(o0, d, 64); o1 += __shfl_xor(o1, d, 64);
        o2 += __shfl_xor(o2, d, 64); o3 += __shfl_xor(o3, d, 64);
        o4 += __shfl_xor(o4, d, 64); o5 += __shfl_xor(o5, d, 64);
    }
    if (lane == 0) {
        float* op = out + (size_t)node * NOUT;
        op[0] = o0 + bm[0]; op[1] = o1 + bm[1]; op[2] = o2 + bm[2];
        op[3] = o3 + bm[3]; op[4] = o4 + bm[4]; op[5] = o5 + bm[5];
    }
}

extern "C" void kernel_launch(void* const* d_in, const int* in_sizes, int n_in,
                              void* d_out, int out_size, void* d_ws, size_t ws_size,
                              hipStream_t stream) {
    const int N = 200000, E = 800000;
    const int C1n = 20000, E1 = 80000;
    const int C2n = 2000, E2 = 8000;

    const float* x  = (const float*)d_in[0];
    const int* ei   = (const int*)d_in[1];
    const int* cl1  = (const int*)d_in[2];
    const int* cl2  = (const int*)d_in[3];
    const int* eic1 = (const int*)d_in[4];
    const int* eic2 = (const int*)d_in[5];
    const float* W1 = (const float*)d_in[6];  const float* b1 = (const float*)d_in[7];
    const float* g1 = (const float*)d_in[8];  const float* bt1 = (const float*)d_in[9];
    const float* W2 = (const float*)d_in[10]; const float* b2 = (const float*)d_in[11];
    const float* g2 = (const float*)d_in[12]; const float* bt2 = (const float*)d_in[13];
    const float* W3 = (const float*)d_in[14]; const float* b3 = (const float*)d_in[15];
    const float* g3 = (const float*)d_in[16]; const float* bt3 = (const float*)d_in[17];
    const float* Wm = (const float*)d_in[18]; const float* bm = (const float*)d_in[19];

    char* wb = (char*)d_ws;
    size_t off = 0;
    auto alloc = [&](size_t nwords) { void* p = wb + off; off += nwords * 4; return p; };
    // --- zero-region ---
    int* degi1 = (int*)alloc(N);   int* fill1 = (int*)alloc(N);
    int* degi2 = (int*)alloc(C1n); int* fill2 = (int*)alloc(C1n);
    int* degi3 = (int*)alloc(C2n); int* fill3 = (int*)alloc(C2n);
    float* st1 = (float*)alloc(128); float* st2 = (float*)alloc(128); float* st3 = (float*)alloc(128);
    float* xp1 = (float*)alloc((size_t)C1n * FIN); float* cnt1 = (float*)alloc(C1n);
    float* xp2 = (float*)alloc((size_t)C2n * FIN); float* cnt2 = (float*)alloc(C2n);
    size_t zero_bytes = off;
    // --- fully-overwritten region ---
    int* rp1 = (int*)alloc(N + 1);   int* col1 = (int*)alloc(E);  float* val1 = (float*)alloc(E);
    int* rp2 = (int*)alloc(C1n + 1); int* col2 = (int*)alloc(E1); float* val2 = (float*)alloc(E1);
    int* rp3 = (int*)alloc(C2n + 1); int* col3 = (int*)alloc(E2); float* val3 = (float*)alloc(E2);
    float* dis1 = (float*)alloc(N); float* dis2 = (float*)alloc(C1n); float* dis3 = (float*)alloc(C2n);
    int* bsum = (int*)alloc(1024);
    float* B1_0 = (float*)alloc((size_t)N * FIN);   float* B1_1 = (float*)alloc((size_t)N * FIN);
    float* B2_0 = (float*)alloc((size_t)C1n * FIN); float* B2_1 = (float*)alloc((size_t)C1n * FIN);
    float* B3_0 = (float*)alloc((size_t)C2n * FIN); float* B3_1 = (float*)alloc((size_t)C2n * FIN);
    float* acc1 = (float*)alloc((size_t)N * NHID);
    float* acc2 = (float*)alloc((size_t)C1n * NHID);
    float* acc3 = (float*)alloc((size_t)C2n * NHID);
    if (off > ws_size) return;  // fail visibly if ws too small

    hipMemsetAsync(d_ws, 0, zero_bytes, stream);

    const int T = 256;
    auto cdiv = [](int a, int b) { return (a + b - 1) / b; };

    auto branch = [&](const float* xin, int n, const int* e, int Ecnt,
                      const float* W, const float* bb, int* degi, int* fill, float* dis,
                      int* rp, int* col, float* val,
                      float* B0, float* Bb1, float* acc, float* st) {
        int ge = cdiv(Ecnt, T), gn = cdiv(n, T);
        int nb = cdiv(n + 1, 256);
        int gp = cdiv(n * 6, T);
        int gg = std::min(cdiv(n, 4), 1280);
        const int WSZ = FIN * NHID;
        // CSR build
        k_hist<<<ge, T, 0, stream>>>(e, Ecnt, degi);
        k_dis<<<gn, T, 0, stream>>>(degi, dis, n);
        k_scan_local<<<nb, 256, 0, stream>>>(degi, n, rp, bsum);
        k_scan_bsum<<<1, 256, 0, stream>>>(bsum, nb);
        k_scan_add<<<nb, 256, 0, stream>>>(rp, bsum, n);
        k_fill<<<ge, T, 0, stream>>>(e, Ecnt, dis, rp, fill, col, val);
        // Tx1 = P(x) -> B0
        k_propg<<<gp, T, 0, stream>>>(rp, col, val, 1.0f, xin, nullptr, B0, n);
        // acc = b + x@W0 + Tx1@W1
        k_gemv2<<<gg, T, 0, stream>>>(xin, B0, W, W + WSZ, bb, acc, nullptr, n);
        // Tx2 = 2P(Tx1) - x -> Bb1
        k_propg<<<gp, T, 0, stream>>>(rp, col, val, 2.0f, B0, xin, Bb1, n);
        // Tx3 = 2P(Tx2) - Tx1 -> B0 (in place over prev)
        k_propg<<<gp, T, 0, stream>>>(rp, col, val, 2.0f, Bb1, B0, B0, n);
        // acc += Tx2@W2 + Tx3@W3
        k_gemv2<<<gg, T, 0, stream>>>(Bb1, B0, W + 2 * WSZ, W + 3 * WSZ, nullptr, acc, nullptr, n);
        // Tx4 = 2P(Tx3) - Tx2 -> Bb1
        k_propg<<<gp, T, 0, stream>>>(rp, col, val, 2.0f, B0, Bb1, Bb1, n);
        // Tx5 = 2P(Tx4) - Tx3 -> B0
        k_propg<<<gp, T, 0, stream>>>(rp, col, val, 2.0f, Bb1, B0, B0, n);
        // acc += Tx4@W4 + Tx5@W5 (+BN stats)
        k_gemv2<<<gg, T, 0, stream>>>(Bb1, B0, W + 4 * WSZ, W + 5 * WSZ, nullptr, acc, st, n);
    };

    // branch 1: full graph
    branch(x, N, ei, E, W1, b1, degi1, fill1, dis1, rp1, col1, val1, B1_0, B1_1, acc1, st1);
    // branch 2
    k_scatter<<<cdiv(N * FIN, T), T, 0, stream>>>(x, cl1, N, xp1, cnt1);
    k_divcnt<<<cdiv(C1n * FIN, T), T, 0, stream>>>(xp1, cnt1, C1n);
    branch(xp1, C1n, eic1, E1, W2, b2, degi2, fill2, dis2, rp2, col2, val2, B2_0, B2_1, acc2, st2);
    k_bnrelu4<<<cdiv(C1n * 16, T), T, 0, stream>>>(acc2, C1n, st2, g2, bt2);
    // branch 3
    k_scatter<<<cdiv(N * FIN, T), T, 0, stream>>>(x, cl2, N, xp2, cnt2);
    k_divcnt<<<cdiv(C2n * FIN, T), T, 0, stream>>>(xp2, cnt2, C2n);
    branch(xp2, C2n, eic2, E2, W3, b3, degi3, fill3, dis3, rp3, col3, val3, B3_0, B3_1, acc3, st3);
    k_bnrelu4<<<cdiv(C2n * 16, T), T, 0, stream>>>(acc3, C2n, st3, g3, bt3);
    // final fused mix
    k_final<<<cdiv(N, 4), T, 0, stream>>>(acc1, st1, g1, bt1, acc2, cl1, acc3, cl2,
                                          x, Wm, bm, (float*)d_out, N);
}

// Round 4
// 912.433 us; speedup vs baseline: 2.8049x; 1.0162x over previous
//
#include <hip/hip_runtime.h>
#include <algorithm>

#define FIN 24
#define NHID 64
#define NMIX 216
#define NOUT 6
#define BN_EPS 1e-5f

// ---------- CSR build ----------
__global__ void k_hist(const int* __restrict__ ei, int E, int* deg) {
    int e = blockIdx.x * blockDim.x + threadIdx.x;
    if (e < E) atomicAdd(&deg[ei[E + e]], 1);
}

__global__ void k_dis(const int* __restrict__ deg, float* dis, int n) {
    int i = blockIdx.x * blockDim.x + threadIdx.x;
    if (i < n) { int v = deg[i]; dis[i] = v > 0 ? rsqrtf((float)v) : 0.f; }
}

// block-local exclusive scan over deg (n+1 elements, deg[i>=n]:=0); totals -> bsum
__global__ void k_scan_local(const int* __restrict__ deg, int n, int* rowptr, int* bsum) {
    __shared__ int s[256];
    int i = blockIdx.x * 256 + threadIdx.x;
    int v = (i < n) ? deg[i] : 0;
    s[threadIdx.x] = v;
    __syncthreads();
#pragma unroll
    for (int off = 1; off < 256; off <<= 1) {
        int x = (threadIdx.x >= off) ? s[threadIdx.x - off] : 0;
        __syncthreads();
        s[threadIdx.x] += x;
        __syncthreads();
    }
    if (i <= n) rowptr[i] = s[threadIdx.x] - v;  // exclusive
    if (threadIdx.x == 255) bsum[blockIdx.x] = s[255];
}

__global__ void k_scan_bsum(int* bsum, int nb) {
    __shared__ int s[256];
    int carry = 0;
    for (int base = 0; base < nb; base += 256) {
        int i = base + threadIdx.x;
        int v = (i < nb) ? bsum[i] : 0;
        s[threadIdx.x] = v;
        __syncthreads();
#pragma unroll
        for (int off = 1; off < 256; off <<= 1) {
            int x = (threadIdx.x >= off) ? s[threadIdx.x - off] : 0;
            __syncthreads();
            s[threadIdx.x] += x;
            __syncthreads();
        }
        if (i < nb) bsum[i] = s[threadIdx.x] - v + carry;
        carry += s[255];
        __syncthreads();
    }
}

__global__ void k_scan_add(int* rowptr, const int* __restrict__ bsum, int n) {
    int i = blockIdx.x * 256 + threadIdx.x;
    if (i <= n) rowptr[i] += bsum[blockIdx.x];
}

__global__ void k_fill(const int* __restrict__ ei, int E, const float* __restrict__ dis,
                       const int* __restrict__ rowptr, int* fill,
                       int* __restrict__ col, float* __restrict__ val) {
    int e = blockIdx.x * blockDim.x + threadIdx.x;
    if (e >= E) return;
    int s = ei[e], d = ei[E + e];
    int slot = rowptr[d] + atomicAdd(&fill[d], 1);
    col[slot] = s;
    val[slot] = -dis[s] * dis[d];
}

// ---------- gather prop, thread per dst node (full 24-float row) ----------
// out[d][:] = scale * sum_e val[e]*h[col[e]][:]  (- prev[d][:]); prev may alias out.
__global__ void k_propg(const int* __restrict__ rowptr, const int* __restrict__ col,
                        const float* __restrict__ val, float scale,
                        const float* __restrict__ h, const float* __restrict__ prev,
                        float* __restrict__ out, int n) {
    int t = blockIdx.x * blockDim.x + threadIdx.x;
    if (t >= n) return;
    int beg = rowptr[t], end = rowptr[t + 1];
    float4 a[6];
#pragma unroll
    for (int q = 0; q < 6; ++q) a[q] = make_float4(0.f, 0.f, 0.f, 0.f);
    for (int e = beg; e < end; ++e) {
        float w = val[e];
        const float4* hp = reinterpret_cast<const float4*>(h + (size_t)col[e] * FIN);
#pragma unroll
        for (int q = 0; q < 6; ++q) {
            float4 hv = hp[q];
            a[q].x = fmaf(w, hv.x, a[q].x);
            a[q].y = fmaf(w, hv.y, a[q].y);
            a[q].z = fmaf(w, hv.z, a[q].z);
            a[q].w = fmaf(w, hv.w, a[q].w);
        }
    }
    float4* op = reinterpret_cast<float4*>(out + (size_t)t * FIN);
    if (prev) {
        const float4* pp = reinterpret_cast<const float4*>(prev + (size_t)t * FIN);
#pragma unroll
        for (int q = 0; q < 6; ++q) {
            float4 pv = pp[q];
            op[q] = make_float4(fmaf(scale, a[q].x, -pv.x), fmaf(scale, a[q].y, -pv.y),
                                fmaf(scale, a[q].z, -pv.z), fmaf(scale, a[q].w, -pv.w));
        }
    } else {
#pragma unroll
        for (int q = 0; q < 6; ++q)
            op[q] = make_float4(scale * a[q].x, scale * a[q].y, scale * a[q].z, scale * a[q].w);
    }
}

// acc[node][j] (=|+=) S1@Wa + S2@Wb (+bias); lane=j, wave-uniform node; opt BN stats.
__global__ void k_gemv2(const float* __restrict__ S1, const float* __restrict__ S2,
                        const float* __restrict__ Wa, const float* __restrict__ Wb,
                        const float* __restrict__ bias, float* __restrict__ acc,
                        float* __restrict__ stats, int n) {
    int j = threadIdx.x & 63;
    int grp = threadIdx.x >> 6;
    float wa[FIN], wb[FIN];
#pragma unroll
    for (int f = 0; f < FIN; ++f) wa[f] = Wa[f * NHID + j];
#pragma unroll
    for (int f = 0; f < FIN; ++f) wb[f] = Wb[f * NHID + j];
    float sum = 0.f, sq = 0.f;
    for (int node = blockIdx.x * 4 + grp; node < n; node += gridDim.x * 4) {
        float a = bias ? bias[j] : acc[(size_t)node * NHID + j];
        const float* s1 = S1 + (size_t)node * FIN;
#pragma unroll
        for (int f = 0; f < FIN; ++f) a = fmaf(s1[f], wa[f], a);
        const float* s2 = S2 + (size_t)node * FIN;
#pragma unroll
        for (int f = 0; f < FIN; ++f) a = fmaf(s2[f], wb[f], a);
        acc[(size_t)node * NHID + j] = a;
        sum += a; sq = fmaf(a, a, sq);
    }
    if (stats) {
        __shared__ float rs[256], rq[256];
        rs[threadIdx.x] = sum; rq[threadIdx.x] = sq;
        __syncthreads();
        if (threadIdx.x < 64) {
            float s = rs[threadIdx.x] + rs[threadIdx.x + 64] + rs[threadIdx.x + 128] + rs[threadIdx.x + 192];
            float q = rq[threadIdx.x] + rq[threadIdx.x + 64] + rq[threadIdx.x + 128] + rq[threadIdx.x + 192];
            atomicAdd(&stats[threadIdx.x], s);
            atomicAdd(&stats[NHID + threadIdx.x], q);
        }
    }
}

// BN coefficients: scsh[0:64]=scale, scsh[64:128]=shift
__global__ void k_bnprep(const float* __restrict__ st, const float* __restrict__ g,
                         const float* __restrict__ bt, float inv_n, float* __restrict__ scsh) {
    int i = threadIdx.x;
    if (i >= NHID) return;
    float m = st[i] * inv_n;
    float v = st[NHID + i] * inv_n - m * m;
    float sc = g[i] * rsqrtf(v + BN_EPS);
    scsh[i] = sc;
    scsh[NHID + i] = fmaf(-m, sc, bt[i]);
}

// in-place BN + ReLU, float4 over [n][64]
__global__ void k_bnrelu4(float* acc, int n, const float* __restrict__ stats,
                          const float* __restrict__ g, const float* __restrict__ bt) {
    int i = blockIdx.x * blockDim.x + threadIdx.x;
    if (i >= n * (NHID / 4)) return;
    int f0 = (i & 15) * 4;
    float inv_n = 1.0f / (float)n;
    float4 v = reinterpret_cast<float4*>(acc)[i];
    float* vp = &v.x;
#pragma unroll
    for (int c = 0; c < 4; ++c) {
        int f = f0 + c;
        float m = stats[f] * inv_n;
        float var = stats[NHID + f] * inv_n - m * m;
        float sc = g[f] * rsqrtf(var + BN_EPS);
        float sh = fmaf(-m, sc, bt[f]);
        vp[c] = fmaxf(fmaf(vp[c], sc, sh), 0.f);
    }
    reinterpret_cast<float4*>(acc)[i] = v;
}

// segment-mean scatter
__global__ void k_scatter(const float* __restrict__ x, const int* __restrict__ cl,
                          int n, float* xp, float* cnt) {
    int idx = blockIdx.x * blockDim.x + threadIdx.x;
    if (idx >= n * FIN) return;
    int node = idx / FIN, f = idx - node * FIN;
    int c = cl[node];
    atomicAdd(&xp[c * FIN + f], x[idx]);
    if (f == 0) atomicAdd(&cnt[c], 1.f);
}

__global__ void k_divcnt(float* xp, const float* __restrict__ cnt, int c) {
    int idx = blockIdx.x * blockDim.x + threadIdx.x;
    if (idx >= c * FIN) return;
    xp[idx] = xp[idx] / fmaxf(cnt[idx / FIN], 1.f);
}

// fused mix: thread per node; BN1 via precomputed scsh (uniform scalar loads);
// Wm/bm indexed with compile-time constants -> scalar loads; 6 reg accumulators.
__global__ void k_final(const float* __restrict__ acc1, const float* __restrict__ scsh,
                        const float* __restrict__ h2, const int* __restrict__ cl1,
                        const float* __restrict__ h3, const int* __restrict__ cl2,
                        const float* __restrict__ x, const float* __restrict__ Wm,
                        const float* __restrict__ bm, float* __restrict__ out, int n) {
    int t = blockIdx.x * blockDim.x + threadIdx.x;
    if (t >= n) return;
    float o[NOUT];
#pragma unroll
    for (int j = 0; j < NOUT; ++j) o[j] = bm[j];
    // section A: BN1+ReLU(acc1) @ Wm[0:64]
    {
        const float4* r4 = reinterpret_cast<const float4*>(acc1 + (size_t)t * NHID);
#pragma unroll
        for (int i4 = 0; i4 < NHID / 4; ++i4) {
            float4 v = r4[i4];
            float hv[4] = {v.x, v.y, v.z, v.w};
#pragma unroll
            for (int c = 0; c < 4; ++c) {
                int i = i4 * 4 + c;
                float h = fmaxf(fmaf(hv[c], scsh[i], scsh[NHID + i]), 0.f);
#pragma unroll
                for (int j = 0; j < NOUT; ++j) o[j] = fmaf(h, Wm[i * NOUT + j], o[j]);
            }
        }
    }
    // section B: h2[cl1[t]] @ Wm[64:128]
    {
        const float4* r4 = reinterpret_cast<const float4*>(h2 + (size_t)cl1[t] * NHID);
#pragma unroll
        for (int i4 = 0; i4 < NHID / 4; ++i4) {
            float4 v = r4[i4];
            float hv[4] = {v.x, v.y, v.z, v.w};
#pragma unroll
            for (int c = 0; c < 4; ++c) {
                int i = NHID + i4 * 4 + c;
#pragma unroll
                for (int j = 0; j < NOUT; ++j) o[j] = fmaf(hv[c], Wm[i * NOUT + j], o[j]);
            }
        }
    }
    // section C: h3[cl2[t]] @ Wm[128:192]
    {
        const float4* r4 = reinterpret_cast<const float4*>(h3 + (size_t)cl2[t] * NHID);
#pragma unroll
        for (int i4 = 0; i4 < NHID / 4; ++i4) {
            float4 v = r4[i4];
            float hv[4] = {v.x, v.y, v.z, v.w};
#pragma unroll
            for (int c = 0; c < 4; ++c) {
                int i = 2 * NHID + i4 * 4 + c;
#pragma unroll
                for (int j = 0; j < NOUT; ++j) o[j] = fmaf(hv[c], Wm[i * NOUT + j], o[j]);
            }
        }
    }
    // section D: x @ Wm[192:216]
    {
        const float4* r4 = reinterpret_cast<const float4*>(x + (size_t)t * FIN);
#pragma unroll
        for (int i4 = 0; i4 < FIN / 4; ++i4) {
            float4 v = r4[i4];
            float hv[4] = {v.x, v.y, v.z, v.w};
#pragma unroll
            for (int c = 0; c < 4; ++c) {
                int i = 3 * NHID + i4 * 4 + c;
#pragma unroll
                for (int j = 0; j < NOUT; ++j) o[j] = fmaf(hv[c], Wm[i * NOUT + j], o[j]);
            }
        }
    }
    float* op = out + (size_t)t * NOUT;
#pragma unroll
    for (int j = 0; j < NOUT; ++j) op[j] = o[j];
}

extern "C" void kernel_launch(void* const* d_in, const int* in_sizes, int n_in,
                              void* d_out, int out_size, void* d_ws, size_t ws_size,
                              hipStream_t stream) {
    const int N = 200000, E = 800000;
    const int C1n = 20000, E1 = 80000;
    const int C2n = 2000, E2 = 8000;

    const float* x  = (const float*)d_in[0];
    const int* ei   = (const int*)d_in[1];
    const int* cl1  = (const int*)d_in[2];
    const int* cl2  = (const int*)d_in[3];
    const int* eic1 = (const int*)d_in[4];
    const int* eic2 = (const int*)d_in[5];
    const float* W1 = (const float*)d_in[6];  const float* b1 = (const float*)d_in[7];
    const float* g1 = (const float*)d_in[8];  const float* bt1 = (const float*)d_in[9];
    const float* W2 = (const float*)d_in[10]; const float* b2 = (const float*)d_in[11];
    const float* g2 = (const float*)d_in[12]; const float* bt2 = (const float*)d_in[13];
    const float* W3 = (const float*)d_in[14]; const float* b3 = (const float*)d_in[15];
    const float* g3 = (const float*)d_in[16]; const float* bt3 = (const float*)d_in[17];
    const float* Wm = (const float*)d_in[18]; const float* bm = (const float*)d_in[19];

    char* wb = (char*)d_ws;
    size_t off = 0;
    // every allocation rounded to 16 B so float4 views are aligned
    auto alloc = [&](size_t nwords) {
        void* p = wb + off; off += ((nwords + 3) & ~(size_t)3) * 4; return p;
    };
    // --- zero-region ---
    int* degi1 = (int*)alloc(N);   int* fill1 = (int*)alloc(N);
    int* degi2 = (int*)alloc(C1n); int* fill2 = (int*)alloc(C1n);
    int* degi3 = (int*)alloc(C2n); int* fill3 = (int*)alloc(C2n);
    float* st1 = (float*)alloc(128); float* st2 = (float*)alloc(128); float* st3 = (float*)alloc(128);
    float* xp1 = (float*)alloc((size_t)C1n * FIN); float* cnt1 = (float*)alloc(C1n);
    float* xp2 = (float*)alloc((size_t)C2n * FIN); float* cnt2 = (float*)alloc(C2n);
    size_t zero_bytes = off;
    // --- fully-overwritten region ---
    int* rp1 = (int*)alloc(N + 1);   int* col1 = (int*)alloc(E);  float* val1 = (float*)alloc(E);
    int* rp2 = (int*)alloc(C1n + 1); int* col2 = (int*)alloc(E1); float* val2 = (float*)alloc(E1);
    int* rp3 = (int*)alloc(C2n + 1); int* col3 = (int*)alloc(E2); float* val3 = (float*)alloc(E2);
    float* dis1 = (float*)alloc(N); float* dis2 = (float*)alloc(C1n); float* dis3 = (float*)alloc(C2n);
    int* bsum = (int*)alloc(1024);
    float* scsh1 = (float*)alloc(128);
    float* B1_0 = (float*)alloc((size_t)N * FIN);   float* B1_1 = (float*)alloc((size_t)N * FIN);
    float* B2_0 = (float*)alloc((size_t)C1n * FIN); float* B2_1 = (float*)alloc((size_t)C1n * FIN);
    float* B3_0 = (float*)alloc((size_t)C2n * FIN); float* B3_1 = (float*)alloc((size_t)C2n * FIN);
    float* acc1 = (float*)alloc((size_t)N * NHID);
    float* acc2 = (float*)alloc((size_t)C1n * NHID);
    float* acc3 = (float*)alloc((size_t)C2n * NHID);
    if (off > ws_size) return;  // fail visibly if ws too small

    hipMemsetAsync(d_ws, 0, zero_bytes, stream);

    const int T = 256;
    auto cdiv = [](int a, int b) { return (a + b - 1) / b; };

    auto branch = [&](const float* xin, int n, const int* e, int Ecnt,
                      const float* W, const float* bb, int* degi, int* fill, float* dis,
                      int* rp, int* col, float* val,
                      float* B0, float* Bb1, float* acc, float* st) {
        int ge = cdiv(Ecnt, T), gn = cdiv(n, T);
        int nb = cdiv(n + 1, 256);
        int gg = std::min(cdiv(n, 4), 1280);
        const int WSZ = FIN * NHID;
        // CSR build
        k_hist<<<ge, T, 0, stream>>>(e, Ecnt, degi);
        k_dis<<<gn, T, 0, stream>>>(degi, dis, n);
        k_scan_local<<<nb, 256, 0, stream>>>(degi, n, rp, bsum);
        k_scan_bsum<<<1, 256, 0, stream>>>(bsum, nb);
        k_scan_add<<<nb, 256, 0, stream>>>(rp, bsum, n);
        k_fill<<<ge, T, 0, stream>>>(e, Ecnt, dis, rp, fill, col, val);
        // Tx1 = P(x) -> B0
        k_propg<<<gn, T, 0, stream>>>(rp, col, val, 1.0f, xin, nullptr, B0, n);
        // acc = b + x@W0 + Tx1@W1
        k_gemv2<<<gg, T, 0, stream>>>(xin, B0, W, W + WSZ, bb, acc, nullptr, n);
        // Tx2 = 2P(Tx1) - x -> Bb1
        k_propg<<<gn, T, 0, stream>>>(rp, col, val, 2.0f, B0, xin, Bb1, n);
        // Tx3 = 2P(Tx2) - Tx1 -> B0 (in place over prev)
        k_propg<<<gn, T, 0, stream>>>(rp, col, val, 2.0f, Bb1, B0, B0, n);
        // acc += Tx2@W2 + Tx3@W3
        k_gemv2<<<gg, T, 0, stream>>>(Bb1, B0, W + 2 * WSZ, W + 3 * WSZ, nullptr, acc, nullptr, n);
        // Tx4 = 2P(Tx3) - Tx2 -> Bb1
        k_propg<<<gn, T, 0, stream>>>(rp, col, val, 2.0f, B0, Bb1, Bb1, n);
        // Tx5 = 2P(Tx4) - Tx3 -> B0
        k_propg<<<gn, T, 0, stream>>>(rp, col, val, 2.0f, Bb1, B0, B0, n);
        // acc += Tx4@W4 + Tx5@W5 (+BN stats)
        k_gemv2<<<gg, T, 0, stream>>>(Bb1, B0, W + 4 * WSZ, W + 5 * WSZ, nullptr, acc, st, n);
    };

    // branch 1: full graph
    branch(x, N, ei, E, W1, b1, degi1, fill1, dis1, rp1, col1, val1, B1_0, B1_1, acc1, st1);
    k_bnprep<<<1, 64, 0, stream>>>(st1, g1, bt1, 1.0f / (float)N, scsh1);
    // branch 2
    k_scatter<<<cdiv(N * FIN, T), T, 0, stream>>>(x, cl1, N, xp1, cnt1);
    k_divcnt<<<cdiv(C1n * FIN, T), T, 0, stream>>>(xp1, cnt1, C1n);
    branch(xp1, C1n, eic1, E1, W2, b2, degi2, fill2, dis2, rp2, col2, val2, B2_0, B2_1, acc2, st2);
    k_bnrelu4<<<cdiv(C1n * 16, T), T, 0, stream>>>(acc2, C1n, st2, g2, bt2);
    // branch 3
    k_scatter<<<cdiv(N * FIN, T), T, 0, stream>>>(x, cl2, N, xp2, cnt2);
    k_divcnt<<<cdiv(C2n * FIN, T), T, 0, stream>>>(xp2, cnt2, C2n);
    branch(xp2, C2n, eic2, E2, W3, b3, degi3, fill3, dis3, rp3, col3, val3, B3_0, B3_1, acc3, st3);
    k_bnrelu4<<<cdiv(C2n * 16, T), T, 0, stream>>>(acc3, C2n, st3, g3, bt3);
    // final fused mix
    k_final<<<cdiv(N, T), T, 0, stream>>>(acc1, scsh1, acc2, cl1, acc3, cl2,
                                          x, Wm, bm, (float*)d_out, N);
}